// Round 1
// baseline (3448.679 us; speedup 1.0000x reference)
//
#include <hip/hip_runtime.h>

// TGCN fused kernel, fp32 baseline.
// Sizes fixed by the reference:
#define BB  8
#define NN1 1024
#define NN2 256
#define DD  16
#define EE  16
#define NCOL (NN2 * DD)   // 4096 columns for the mode-0 GEMM

// ---------------------------------------------------------------------------
// Kernel 1: y0[b,p,c] = sum_i adj0[i,p] * x[b,i,c]   (c = j*16+d flattened)
// GEMM per batch: M=N1 (p), N=4096 (c), K=N1 (i). A = adj0 (K x M row-major,
// accessed [i][p] -> coalesced along p, no transpose needed).
// Block tile 128x128, BK=16, 256 threads, 8x8 microtile with split-64 layout.
// ---------------------------------------------------------------------------
#define BM 128
#define BN 128
#define BK 16

__global__ __launch_bounds__(256)
void k_mode0(const float* __restrict__ A0, const float* __restrict__ X,
             float* __restrict__ Y) {
  __shared__ float As[BK][BM];
  __shared__ float Bs[BK][BN];

  const int b  = blockIdx.z;
  const int pm = blockIdx.y * BM;
  const int cn = blockIdx.x * BN;
  const int t  = threadIdx.x;
  const int tx = t & 15;   // column group
  const int ty = t >> 4;   // row group

  const float* Xb = X + (size_t)b * NN1 * NCOL;

  float acc[8][8];
#pragma unroll
  for (int i = 0; i < 8; ++i)
#pragma unroll
    for (int j = 0; j < 8; ++j) acc[i][j] = 0.f;

  for (int k0 = 0; k0 < NN1; k0 += BK) {
    // cooperative loads: 16x128 floats = 512 float4 per tile, 2 per thread
#pragma unroll
    for (int l = 0; l < 2; ++l) {
      const int f   = t + l * 256;
      const int row = f >> 5;          // 0..15
      const int col = (f & 31) << 2;   // 0..124
      float4 va = *reinterpret_cast<const float4*>(
          &A0[(size_t)(k0 + row) * NN1 + pm + col]);
      *reinterpret_cast<float4*>(&As[row][col]) = va;
      float4 vb = *reinterpret_cast<const float4*>(
          &Xb[(size_t)(k0 + row) * NCOL + cn + col]);
      *reinterpret_cast<float4*>(&Bs[row][col]) = vb;
    }
    __syncthreads();

#pragma unroll
    for (int kk = 0; kk < BK; ++kk) {
      float a[8], bf[8];
      *reinterpret_cast<float4*>(&a[0])  = *reinterpret_cast<const float4*>(&As[kk][ty * 4]);
      *reinterpret_cast<float4*>(&a[4])  = *reinterpret_cast<const float4*>(&As[kk][64 + ty * 4]);
      *reinterpret_cast<float4*>(&bf[0]) = *reinterpret_cast<const float4*>(&Bs[kk][tx * 4]);
      *reinterpret_cast<float4*>(&bf[4]) = *reinterpret_cast<const float4*>(&Bs[kk][64 + tx * 4]);
#pragma unroll
      for (int i = 0; i < 8; ++i)
#pragma unroll
        for (int j = 0; j < 8; ++j)
          acc[i][j] = fmaf(a[i], bf[j], acc[i][j]);
    }
    __syncthreads();
  }

  float* Yb = Y + (size_t)b * NN1 * NCOL;
#pragma unroll
  for (int i = 0; i < 8; ++i) {
    const int p = pm + ((i < 4) ? (ty * 4 + i) : (64 + ty * 4 + (i - 4)));
    float4 v0 = make_float4(acc[i][0], acc[i][1], acc[i][2], acc[i][3]);
    float4 v1 = make_float4(acc[i][4], acc[i][5], acc[i][6], acc[i][7]);
    *reinterpret_cast<float4*>(&Yb[(size_t)p * NCOL + cn + tx * 4]) = v0;
    *reinterpret_cast<float4*>(&Yb[(size_t)p * NCOL + cn + 64 + tx * 4]) = v1;
  }
}

// ---------------------------------------------------------------------------
// Kernel 2: per (b,p) slice (one block, 256 threads, thread q = row of N2):
//   r[q,e]  = x[q,:]@W + y0[q,:]@W_s0 + (b+b_s0+b_s1+b_s01)[e]
//   s[q,e]  = x[q,:]@W_s1 + y0[q,:]@W_s01          (staged in LDS)
//   t[q,e]  = sum_j adj1[j,q] * s[j,e]             (merged mode-1 aggregation)
//   out     = relu(r + t)
// ---------------------------------------------------------------------------
#define SPAD 20  // 16 + 4 pad: 80B row stride keeps 16B alignment, spreads banks

__global__ __launch_bounds__(256)
void k_fused(const float* __restrict__ x, const float* __restrict__ y0,
             const float* __restrict__ adj1,
             const float* __restrict__ W,   const float* __restrict__ bW,
             const float* __restrict__ W0,  const float* __restrict__ b0,
             const float* __restrict__ W1,  const float* __restrict__ b1,
             const float* __restrict__ W01, const float* __restrict__ b01,
             float* __restrict__ out) {
  __shared__ float sW[4][DD][EE];   // W, W_s0, W_s1, W_s01
  __shared__ float sbias[EE];
  __shared__ float ssum[NN2][SPAD];

  const int t = threadIdx.x;

  {
    const int m = t >> 6;       // which matrix
    const int r = t & 63;       // which float4 of 64
    const float* Wp = (m == 0) ? W : (m == 1) ? W0 : (m == 2) ? W1 : W01;
    reinterpret_cast<float4*>(&sW[m][0][0])[r] =
        reinterpret_cast<const float4*>(Wp)[r];
  }
  if (t < EE) sbias[t] = bW[t] + b0[t] + b1[t] + b01[t];
  __syncthreads();

  const int q = t;
  const size_t base = (size_t)blockIdx.x * (NN2 * DD) + (size_t)q * DD;

  float xr[DD], yr[DD];
#pragma unroll
  for (int v = 0; v < 4; ++v) {
    *reinterpret_cast<float4*>(&xr[v * 4]) =
        *reinterpret_cast<const float4*>(&x[base + v * 4]);
    *reinterpret_cast<float4*>(&yr[v * 4]) =
        *reinterpret_cast<const float4*>(&y0[base + v * 4]);
  }

  float r[EE], sr[EE];
#pragma unroll
  for (int e = 0; e < EE; ++e) { r[e] = sbias[e]; sr[e] = 0.f; }

#pragma unroll
  for (int d = 0; d < DD; ++d) {
    const float xd = xr[d], yd = yr[d];
#pragma unroll
    for (int e = 0; e < EE; ++e) {
      r[e]  = fmaf(xd, sW[0][d][e], r[e]);
      r[e]  = fmaf(yd, sW[1][d][e], r[e]);
      sr[e] = fmaf(xd, sW[2][d][e], sr[e]);
      sr[e] = fmaf(yd, sW[3][d][e], sr[e]);
    }
  }

#pragma unroll
  for (int v = 0; v < 4; ++v)
    *reinterpret_cast<float4*>(&ssum[q][v * 4]) =
        *reinterpret_cast<const float4*>(&sr[v * 4]);
  __syncthreads();

  float acc[EE];
#pragma unroll
  for (int e = 0; e < EE; ++e) acc[e] = 0.f;

#pragma unroll 4
  for (int j = 0; j < NN2; ++j) {
    const float a = adj1[j * NN2 + q];   // coalesced; adj1 is L2-resident (256KB)
#pragma unroll
    for (int e = 0; e < EE; ++e) acc[e] = fmaf(a, ssum[j][e], acc[e]);
  }

  const size_t obase = (size_t)blockIdx.x * (NN2 * EE) + (size_t)q * EE;
  float o[EE];
#pragma unroll
  for (int e = 0; e < EE; ++e) o[e] = fmaxf(r[e] + acc[e], 0.f);
#pragma unroll
  for (int v = 0; v < 4; ++v)
    *reinterpret_cast<float4*>(&out[obase + v * 4]) =
        *reinterpret_cast<const float4*>(&o[v * 4]);
}

// ---------------------------------------------------------------------------
extern "C" void kernel_launch(void* const* d_in, const int* in_sizes, int n_in,
                              void* d_out, int out_size, void* d_ws, size_t ws_size,
                              hipStream_t stream) {
  const float* x    = (const float*)d_in[0];
  const float* adj0 = (const float*)d_in[1];
  const float* adj1 = (const float*)d_in[2];
  const float* W    = (const float*)d_in[3];
  const float* bW   = (const float*)d_in[4];
  const float* Ws0  = (const float*)d_in[5];
  const float* bs0  = (const float*)d_in[6];
  const float* Ws1  = (const float*)d_in[7];
  const float* bs1  = (const float*)d_in[8];
  const float* Ws01 = (const float*)d_in[9];
  const float* bs01 = (const float*)d_in[10];
  float* out = (float*)d_out;
  float* y0  = (float*)d_ws;

  const size_t SLICE = (size_t)NN1 * NN2 * DD;  // per-batch elements (= out stride too, E==D)

  // Chunk batches through the workspace (y0 per batch = 16.8 MB).
  int nb_max = (int)(ws_size / (SLICE * sizeof(float)));
  if (nb_max > BB) nb_max = BB;
  if (nb_max < 1)  nb_max = 1;

  for (int c0 = 0; c0 < BB; c0 += nb_max) {
    const int nb = (BB - c0 < nb_max) ? (BB - c0) : nb_max;
    dim3 g1(NCOL / BN, NN1 / BM, nb);
    k_mode0<<<g1, 256, 0, stream>>>(adj0, x + (size_t)c0 * SLICE, y0);
    dim3 g2(nb * NN1);
    k_fused<<<g2, 256, 0, stream>>>(x + (size_t)c0 * SLICE, y0, adj1,
                                    W, bW, Ws0, bs0, Ws1, bs1, Ws01, bs01,
                                    out + (size_t)c0 * SLICE);
  }
}

// Round 2
// 1055.261 us; speedup vs baseline: 3.2681x; 3.2681x over previous
//
#include <hip/hip_runtime.h>

// TGCN fused pipeline, fp32.
#define BB  8
#define NN1 1024
#define NN2 256
#define DD  16
#define EE  16
#define NCOL (NN2 * DD)   // 4096

// ---------------------------------------------------------------------------
// Kernel 1: y0[b,p,c] = sum_i adj0[i,p] * x[b,i,c]
// GEMM per batch: M=N1(p), N=4096(c), K=N1(i). 128x128x16 tile, 8x8 micro.
// ---------------------------------------------------------------------------
#define BM 128
#define BN 128
#define BK 16

__global__ __launch_bounds__(256)
void k_mode0(const float* __restrict__ A0, const float* __restrict__ X,
             float* __restrict__ Y) {
  __shared__ float As[BK][BM];
  __shared__ float Bs[BK][BN];

  const int b  = blockIdx.z;
  const int pm = blockIdx.y * BM;
  const int cn = blockIdx.x * BN;
  const int t  = threadIdx.x;
  const int tx = t & 15;
  const int ty = t >> 4;

  const float* Xb = X + (size_t)b * NN1 * NCOL;

  float acc[8][8];
#pragma unroll
  for (int i = 0; i < 8; ++i)
#pragma unroll
    for (int j = 0; j < 8; ++j) acc[i][j] = 0.f;

  for (int k0 = 0; k0 < NN1; k0 += BK) {
#pragma unroll
    for (int l = 0; l < 2; ++l) {
      const int f   = t + l * 256;
      const int row = f >> 5;
      const int col = (f & 31) << 2;
      float4 va = *reinterpret_cast<const float4*>(
          &A0[(size_t)(k0 + row) * NN1 + pm + col]);
      *reinterpret_cast<float4*>(&As[row][col]) = va;
      float4 vb = *reinterpret_cast<const float4*>(
          &Xb[(size_t)(k0 + row) * NCOL + cn + col]);
      *reinterpret_cast<float4*>(&Bs[row][col]) = vb;
    }
    __syncthreads();

#pragma unroll
    for (int kk = 0; kk < BK; ++kk) {
      float a[8], bf[8];
      *reinterpret_cast<float4*>(&a[0])  = *reinterpret_cast<const float4*>(&As[kk][ty * 4]);
      *reinterpret_cast<float4*>(&a[4])  = *reinterpret_cast<const float4*>(&As[kk][64 + ty * 4]);
      *reinterpret_cast<float4*>(&bf[0]) = *reinterpret_cast<const float4*>(&Bs[kk][tx * 4]);
      *reinterpret_cast<float4*>(&bf[4]) = *reinterpret_cast<const float4*>(&Bs[kk][64 + tx * 4]);
#pragma unroll
      for (int i = 0; i < 8; ++i)
#pragma unroll
        for (int j = 0; j < 8; ++j)
          acc[i][j] = fmaf(a[i], bf[j], acc[i][j]);
    }
    __syncthreads();
  }

  float* Yb = Y + (size_t)b * NN1 * NCOL;
#pragma unroll
  for (int i = 0; i < 8; ++i) {
    const int p = pm + ((i < 4) ? (ty * 4 + i) : (64 + ty * 4 + (i - 4)));
    float4 v0 = make_float4(acc[i][0], acc[i][1], acc[i][2], acc[i][3]);
    float4 v1 = make_float4(acc[i][4], acc[i][5], acc[i][6], acc[i][7]);
    *reinterpret_cast<float4*>(&Yb[(size_t)p * NCOL + cn + tx * 4]) = v0;
    *reinterpret_cast<float4*>(&Yb[(size_t)p * NCOL + cn + 64 + tx * 4]) = v1;
  }
}

// ---------------------------------------------------------------------------
// Kernel 2: per (b,p) slice, thread j:
//   r[j,e] = x[j,:]@W + y0[j,:]@W_s0 + (b+b_s0+b_s1+b_s01)[e]  -> d_out
//   s[j,e] = x[j,:]@W_s1 + y0[j,:]@W_s01
//   s written TRANSPOSED over the y0 slice: s_t[e*256 + j]  (in-place)
// ---------------------------------------------------------------------------
__global__ __launch_bounds__(256)
void k_proj(const float* __restrict__ x, float* __restrict__ y0ws,
            const float* __restrict__ W,   const float* __restrict__ bW,
            const float* __restrict__ W0,  const float* __restrict__ b0,
            const float* __restrict__ W1,  const float* __restrict__ b1,
            const float* __restrict__ W01, const float* __restrict__ b01,
            float* __restrict__ out) {
  __shared__ float sW[4][DD][EE];
  __shared__ float sbias[EE];

  const int t = threadIdx.x;
  {
    const int m = t >> 6;
    const int r = t & 63;
    const float* Wp = (m == 0) ? W : (m == 1) ? W0 : (m == 2) ? W1 : W01;
    reinterpret_cast<float4*>(&sW[m][0][0])[r] =
        reinterpret_cast<const float4*>(Wp)[r];
  }
  if (t < EE) sbias[t] = bW[t] + b0[t] + b1[t] + b01[t];
  __syncthreads();

  const size_t sbase = (size_t)blockIdx.x * NCOL;  // slice base
  const size_t base  = sbase + (size_t)t * DD;

  float xr[DD], yr[DD];
#pragma unroll
  for (int v = 0; v < 4; ++v) {
    *reinterpret_cast<float4*>(&xr[v * 4]) =
        *reinterpret_cast<const float4*>(&x[base + v * 4]);
    *reinterpret_cast<float4*>(&yr[v * 4]) =
        *reinterpret_cast<const float4*>(&y0ws[base + v * 4]);
  }

  float r[EE], s[EE];
#pragma unroll
  for (int e = 0; e < EE; ++e) { r[e] = sbias[e]; s[e] = 0.f; }

#pragma unroll
  for (int d = 0; d < DD; ++d) {
    const float xd = xr[d], yd = yr[d];
#pragma unroll
    for (int e = 0; e < EE; ++e) {
      r[e] = fmaf(xd, sW[0][d][e], r[e]);
      r[e] = fmaf(yd, sW[1][d][e], r[e]);
      s[e] = fmaf(xd, sW[2][d][e], s[e]);
      s[e] = fmaf(yd, sW[3][d][e], s[e]);
    }
  }

  // all y0 reads (each thread its own row, already in regs) complete before
  // any thread overwrites the slice with s_t
  __syncthreads();

#pragma unroll
  for (int v = 0; v < 4; ++v)
    *reinterpret_cast<float4*>(&out[base + v * 4]) =
        *reinterpret_cast<const float4*>(&r[v * 4]);
#pragma unroll
  for (int e = 0; e < EE; ++e)
    y0ws[sbase + (size_t)e * NN2 + t] = s[e];   // coalesced 256B rows
}

// ---------------------------------------------------------------------------
// Kernel 3: C[q, m] = sum_j adj1[j,q] * s_t[m, j]   (m = bp*16+e, M=256 q rows)
// then out[bp, q, e] = relu(r + C).  Tile 128q x 128m x 16j, 8x8 micro.
// ---------------------------------------------------------------------------
#define CBK 16

__global__ __launch_bounds__(256)
void k_mode1(const float* __restrict__ st, const float* __restrict__ adj1,
             float* __restrict__ out) {
  __shared__ float As[CBK][128];   // adj1 [j][q] tile
  __shared__ float Bs[CBK][128];   // s_t transposed tile: [j][m]

  const int t  = threadIdx.x;
  const int tx = t & 15;
  const int ty = t >> 4;
  const int q0 = blockIdx.x * 128;
  const int m0 = blockIdx.y * 128;

  float acc[8][8];
#pragma unroll
  for (int i = 0; i < 8; ++i)
#pragma unroll
    for (int j = 0; j < 8; ++j) acc[i][j] = 0.f;

  for (int k0 = 0; k0 < NN2; k0 += CBK) {
#pragma unroll
    for (int l = 0; l < 2; ++l) {
      const int f   = t + l * 256;
      const int row = f >> 5;
      const int col = (f & 31) << 2;
      *reinterpret_cast<float4*>(&As[row][col]) =
          *reinterpret_cast<const float4*>(&adj1[(size_t)(k0 + row) * NN2 + q0 + col]);
    }
#pragma unroll
    for (int l = 0; l < 2; ++l) {
      const int f  = t + l * 256;
      const int ml = f & 127;
      const int jg = f >> 7;   // 0..3
      float4 v = *reinterpret_cast<const float4*>(
          &st[(size_t)(m0 + ml) * NN2 + k0 + jg * 4]);
      Bs[jg * 4 + 0][ml] = v.x;
      Bs[jg * 4 + 1][ml] = v.y;
      Bs[jg * 4 + 2][ml] = v.z;
      Bs[jg * 4 + 3][ml] = v.w;
    }
    __syncthreads();

#pragma unroll
    for (int kk = 0; kk < CBK; ++kk) {
      float a[8], bf[8];
      *reinterpret_cast<float4*>(&a[0])  = *reinterpret_cast<const float4*>(&As[kk][ty * 4]);
      *reinterpret_cast<float4*>(&a[4])  = *reinterpret_cast<const float4*>(&As[kk][64 + ty * 4]);
      *reinterpret_cast<float4*>(&bf[0]) = *reinterpret_cast<const float4*>(&Bs[kk][tx * 4]);
      *reinterpret_cast<float4*>(&bf[4]) = *reinterpret_cast<const float4*>(&Bs[kk][64 + tx * 4]);
#pragma unroll
      for (int i = 0; i < 8; ++i)
#pragma unroll
        for (int j = 0; j < 8; ++j)
          acc[i][j] = fmaf(a[i], bf[j], acc[i][j]);
    }
    __syncthreads();
  }

#pragma unroll
  for (int i = 0; i < 8; ++i) {
    const int q = q0 + ((i < 4) ? (ty * 4 + i) : (64 + ty * 4 + (i - 4)));
#pragma unroll
    for (int jh = 0; jh < 2; ++jh) {
      const int mbase = m0 + jh * 64 + tx * 4;   // 4 consecutive m within one e-16 group
      const int bp = mbase >> 4;
      const int e0 = mbase & 15;
      const size_t o = (size_t)bp * (NN2 * EE) + (size_t)q * EE + e0;
      float4 r4 = *reinterpret_cast<const float4*>(&out[o]);
      float4 w;
      w.x = fmaxf(r4.x + acc[i][jh * 4 + 0], 0.f);
      w.y = fmaxf(r4.y + acc[i][jh * 4 + 1], 0.f);
      w.z = fmaxf(r4.z + acc[i][jh * 4 + 2], 0.f);
      w.w = fmaxf(r4.w + acc[i][jh * 4 + 3], 0.f);
      *reinterpret_cast<float4*>(&out[o]) = w;
    }
  }
}

// ---------------------------------------------------------------------------
extern "C" void kernel_launch(void* const* d_in, const int* in_sizes, int n_in,
                              void* d_out, int out_size, void* d_ws, size_t ws_size,
                              hipStream_t stream) {
  const float* x    = (const float*)d_in[0];
  const float* adj0 = (const float*)d_in[1];
  const float* adj1 = (const float*)d_in[2];
  const float* W    = (const float*)d_in[3];
  const float* bW   = (const float*)d_in[4];
  const float* Ws0  = (const float*)d_in[5];
  const float* bs0  = (const float*)d_in[6];
  const float* Ws1  = (const float*)d_in[7];
  const float* bs1  = (const float*)d_in[8];
  const float* Ws01 = (const float*)d_in[9];
  const float* bs01 = (const float*)d_in[10];
  float* out = (float*)d_out;
  float* y0  = (float*)d_ws;

  const size_t SLICE = (size_t)NN1 * NN2 * DD;   // per-batch elements

  int nb_max = (int)(ws_size / (SLICE * sizeof(float)));
  if (nb_max > BB) nb_max = BB;
  if (nb_max < 1)  nb_max = 1;

  for (int c0 = 0; c0 < BB; c0 += nb_max) {
    const int nb = (BB - c0 < nb_max) ? (BB - c0) : nb_max;
    const float* xc  = x   + (size_t)c0 * SLICE;
    float*       oc  = out + (size_t)c0 * SLICE;

    dim3 g1(NCOL / BN, NN1 / BM, nb);
    k_mode0<<<g1, 256, 0, stream>>>(adj0, xc, y0);

    dim3 g2(nb * NN1);
    k_proj<<<g2, 256, 0, stream>>>(xc, y0, W, bW, Ws0, bs0, Ws1, bs1,
                                   Ws01, bs01, oc);

    dim3 g3(NN2 / 128, nb * NN1 * EE / 128);
    k_mode1<<<g3, 256, 0, stream>>>(y0, adj1, oc);
  }
}

// Round 3
// 486.829 us; speedup vs baseline: 7.0840x; 2.1676x over previous
//
#include <hip/hip_runtime.h>

#define BB  8
#define NN1 1024
#define NN2 256
#define DD  16
#define EE  16
#define NCOL (NN2 * DD)   // 4096

using bf16x8 = __attribute__((ext_vector_type(8))) short;
using f32x4  = __attribute__((ext_vector_type(4))) float;

__device__ __forceinline__ ushort f2bf(float x) {
  unsigned u = __float_as_uint(x);
  unsigned r = (u + 0x7FFFu + ((u >> 16) & 1u)) >> 16;
  return (ushort)r;
}

#define GLDS16(g, l)                                                       \
  __builtin_amdgcn_global_load_lds(                                        \
      (const __attribute__((address_space(1))) void*)(g),                  \
      (__attribute__((address_space(3))) void*)(l), 16, 0, 0)

// ---------------------------------------------------------------------------
// k_prep: transpose + fp32->bf16 + chunk-swizzle.
// src: fp32 [1024(k)][nr] (per batch). dst: bf16 [nr][1024(k)] rows where
// within each 64B block the 16B chunks are permuted: phys chunk g holds
// logical chunk g ^ ((row>>1)&3). GEMM then stages tiles LINEARLY via
// global_load_lds and applies the same XOR on ds_read -> 2-way banks (free).
// ---------------------------------------------------------------------------
__global__ __launch_bounds__(256)
void k_prep(const float* __restrict__ src, ushort* __restrict__ dst,
            int nr, size_t srcBatch, size_t dstBatch) {
  __shared__ float tile[64][65];
  const int t = threadIdx.x;
  const int r0 = blockIdx.x * 64;   // output-row tile (p or c)
  const int k0 = blockIdx.y * 64;   // k tile
  const float* s = src + (size_t)blockIdx.z * srcBatch;
  ushort* d = dst + (size_t)blockIdx.z * dstBatch;

#pragma unroll
  for (int it = 0; it < 4; ++it) {
    const int kr = it * 16 + (t >> 4);
    const int rc = (t & 15) * 4;
    float4 v = *reinterpret_cast<const float4*>(&s[(size_t)(k0 + kr) * nr + r0 + rc]);
    tile[kr][rc] = v.x; tile[kr][rc + 1] = v.y;
    tile[kr][rc + 2] = v.z; tile[kr][rc + 3] = v.w;
  }
  __syncthreads();

#pragma unroll
  for (int pass = 0; pass < 2; ++pass) {
    const int task = t + pass * 256;
    const int pr = task >> 3;   // local row 0..63
    const int gl = task & 7;    // 16B chunk within 64-k span
    const int r = r0 + pr;
    const int f = (r >> 1) & 3;
    const int klb = (gl >> 2) * 32 + ((gl & 3) ^ f) * 8;  // source k (local)
    unsigned w[4];
#pragma unroll
    for (int e2 = 0; e2 < 4; ++e2) {
      const ushort lo = f2bf(tile[klb + e2 * 2][pr]);
      const ushort hi = f2bf(tile[klb + e2 * 2 + 1][pr]);
      w[e2] = (unsigned)lo | ((unsigned)hi << 16);
    }
    *reinterpret_cast<uint4*>(&d[(size_t)r * 1024 + k0 + gl * 8]) =
        *reinterpret_cast<const uint4*>(w);
  }
}

// ---------------------------------------------------------------------------
// k_mode0_mfma: Y[b][p][c] = sum_k adj0[k][p] * X[b][k][c]  (fp32 out)
// A = At[p][k] bf16 (swizzled), B = Xt[b][c][k] bf16 (swizzled).
// 128x128 tile, BK=32, 4 waves (2x2), each wave 4x4 of 16x16x32 MFMA.
// ---------------------------------------------------------------------------
__global__ __launch_bounds__(256)
void k_mode0_mfma(const ushort* __restrict__ At, const ushort* __restrict__ Xt,
                  float* __restrict__ Y) {
  __shared__ ushort As[128 * 32];
  __shared__ ushort Bs[128 * 32];

  const int t = threadIdx.x;
  const int lane = t & 63;
  const int wid = t >> 6;
  const int wm = wid >> 1, wn = wid & 1;
  const int b  = blockIdx.x >> 5;           // 32 n-tiles per batch
  const int c0 = (blockIdx.x & 31) << 7;
  const int p0 = blockIdx.y << 7;

  const ushort* Bb = Xt + (size_t)b * (NCOL * 1024);

  f32x4 acc[4][4];
#pragma unroll
  for (int i = 0; i < 4; ++i)
#pragma unroll
    for (int j = 0; j < 4; ++j) acc[i][j] = (f32x4)0.f;

  // staging: each wave copies 32 rows of each tile (2 issues x 16 rows)
  const int srow = wid * 32 + (lane >> 2);
  const int schk = (lane & 3) * 8;
  const size_t aoff0 = (size_t)(p0 + srow) * 1024 + schk;
  const size_t boff0 = (size_t)(c0 + srow) * 1024 + schk;
  ushort* lA0 = As + (wid * 32) * 32;
  ushort* lA1 = As + (wid * 32 + 16) * 32;
  ushort* lB0 = Bs + (wid * 32) * 32;
  ushort* lB1 = Bs + (wid * 32 + 16) * 32;

  // fragment LDS offsets (fixed across K)
  const int lm = lane & 15, g = lane >> 4;
  int aro[4], bro[4];
#pragma unroll
  for (int f = 0; f < 4; ++f) {
    const int ra = wm * 64 + f * 16 + lm;
    aro[f] = ra * 32 + ((g ^ ((ra >> 1) & 3)) << 3);
    const int rb = wn * 64 + f * 16 + lm;
    bro[f] = rb * 32 + ((g ^ ((rb >> 1) & 3)) << 3);
  }

  for (int k0 = 0; k0 < 1024; k0 += 32) {
    GLDS16(At + aoff0 + k0, lA0);
    GLDS16(At + aoff0 + 16 * 1024 + k0, lA1);
    GLDS16(Bb + boff0 + k0, lB0);
    GLDS16(Bb + boff0 + 16 * 1024 + k0, lB1);
    asm volatile("s_waitcnt vmcnt(0)" ::: "memory");
    __syncthreads();

    bf16x8 af[4], bfr[4];
#pragma unroll
    for (int f = 0; f < 4; ++f) af[f] = *reinterpret_cast<const bf16x8*>(As + aro[f]);
#pragma unroll
    for (int f = 0; f < 4; ++f) bfr[f] = *reinterpret_cast<const bf16x8*>(Bs + bro[f]);

#pragma unroll
    for (int i = 0; i < 4; ++i)
#pragma unroll
      for (int j = 0; j < 4; ++j)
        acc[i][j] = __builtin_amdgcn_mfma_f32_16x16x32_bf16(af[i], bfr[j], acc[i][j], 0, 0, 0);
    __syncthreads();
  }

  float* Yb = Y + (size_t)b * (NN1 * NCOL);
  const int orow = (lane >> 4) * 4;   // C/D: row=(lane>>4)*4+e, col=lane&15
  const int ocol = lane & 15;
#pragma unroll
  for (int i = 0; i < 4; ++i)
#pragma unroll
    for (int j = 0; j < 4; ++j) {
      const int p = p0 + wm * 64 + i * 16 + orow;
      const int c = c0 + wn * 64 + j * 16 + ocol;
      float* dst = Yb + (size_t)p * NCOL + c;
#pragma unroll
      for (int e = 0; e < 4; ++e) dst[(size_t)e * NCOL] = acc[i][j][e];
    }
}

// ---------------------------------------------------------------------------
// k_proj (unchanged from R2)
// ---------------------------------------------------------------------------
__global__ __launch_bounds__(256)
void k_proj(const float* __restrict__ x, float* __restrict__ y0ws,
            const float* __restrict__ W,   const float* __restrict__ bW,
            const float* __restrict__ W0,  const float* __restrict__ b0,
            const float* __restrict__ W1,  const float* __restrict__ b1,
            const float* __restrict__ W01, const float* __restrict__ b01,
            float* __restrict__ out) {
  __shared__ float sW[4][DD][EE];
  __shared__ float sbias[EE];

  const int t = threadIdx.x;
  {
    const int m = t >> 6;
    const int r = t & 63;
    const float* Wp = (m == 0) ? W : (m == 1) ? W0 : (m == 2) ? W1 : W01;
    reinterpret_cast<float4*>(&sW[m][0][0])[r] =
        reinterpret_cast<const float4*>(Wp)[r];
  }
  if (t < EE) sbias[t] = bW[t] + b0[t] + b1[t] + b01[t];
  __syncthreads();

  const size_t sbase = (size_t)blockIdx.x * NCOL;
  const size_t base  = sbase + (size_t)t * DD;

  float xr[DD], yr[DD];
#pragma unroll
  for (int v = 0; v < 4; ++v) {
    *reinterpret_cast<float4*>(&xr[v * 4]) =
        *reinterpret_cast<const float4*>(&x[base + v * 4]);
    *reinterpret_cast<float4*>(&yr[v * 4]) =
        *reinterpret_cast<const float4*>(&y0ws[base + v * 4]);
  }

  float r[EE], s[EE];
#pragma unroll
  for (int e = 0; e < EE; ++e) { r[e] = sbias[e]; s[e] = 0.f; }

#pragma unroll
  for (int d = 0; d < DD; ++d) {
    const float xd = xr[d], yd = yr[d];
#pragma unroll
    for (int e = 0; e < EE; ++e) {
      r[e] = fmaf(xd, sW[0][d][e], r[e]);
      r[e] = fmaf(yd, sW[1][d][e], r[e]);
      s[e] = fmaf(xd, sW[2][d][e], s[e]);
      s[e] = fmaf(yd, sW[3][d][e], s[e]);
    }
  }

  __syncthreads();

#pragma unroll
  for (int v = 0; v < 4; ++v)
    *reinterpret_cast<float4*>(&out[base + v * 4]) =
        *reinterpret_cast<const float4*>(&r[v * 4]);
#pragma unroll
  for (int e = 0; e < EE; ++e)
    y0ws[sbase + (size_t)e * NN2 + t] = s[e];
}

// ---------------------------------------------------------------------------
// k_mode1 (unchanged from R2)
// ---------------------------------------------------------------------------
#define CBK 16

__global__ __launch_bounds__(256)
void k_mode1(const float* __restrict__ st, const float* __restrict__ adj1,
             float* __restrict__ out) {
  __shared__ float As[CBK][128];
  __shared__ float Bs[CBK][128];

  const int t  = threadIdx.x;
  const int tx = t & 15;
  const int ty = t >> 4;
  const int q0 = blockIdx.x * 128;
  const int m0 = blockIdx.y * 128;

  float acc[8][8];
#pragma unroll
  for (int i = 0; i < 8; ++i)
#pragma unroll
    for (int j = 0; j < 8; ++j) acc[i][j] = 0.f;

  for (int k0 = 0; k0 < NN2; k0 += CBK) {
#pragma unroll
    for (int l = 0; l < 2; ++l) {
      const int f   = t + l * 256;
      const int row = f >> 5;
      const int col = (f & 31) << 2;
      *reinterpret_cast<float4*>(&As[row][col]) =
          *reinterpret_cast<const float4*>(&adj1[(size_t)(k0 + row) * NN2 + q0 + col]);
    }
#pragma unroll
    for (int l = 0; l < 2; ++l) {
      const int f  = t + l * 256;
      const int ml = f & 127;
      const int jg = f >> 7;
      float4 v = *reinterpret_cast<const float4*>(
          &st[(size_t)(m0 + ml) * NN2 + k0 + jg * 4]);
      Bs[jg * 4 + 0][ml] = v.x;
      Bs[jg * 4 + 1][ml] = v.y;
      Bs[jg * 4 + 2][ml] = v.z;
      Bs[jg * 4 + 3][ml] = v.w;
    }
    __syncthreads();

#pragma unroll
    for (int kk = 0; kk < CBK; ++kk) {
      float a[8], bf[8];
      *reinterpret_cast<float4*>(&a[0])  = *reinterpret_cast<const float4*>(&As[kk][ty * 4]);
      *reinterpret_cast<float4*>(&a[4])  = *reinterpret_cast<const float4*>(&As[kk][64 + ty * 4]);
      *reinterpret_cast<float4*>(&bf[0]) = *reinterpret_cast<const float4*>(&Bs[kk][tx * 4]);
      *reinterpret_cast<float4*>(&bf[4]) = *reinterpret_cast<const float4*>(&Bs[kk][64 + tx * 4]);
#pragma unroll
      for (int i = 0; i < 8; ++i)
#pragma unroll
        for (int j = 0; j < 8; ++j)
          acc[i][j] = fmaf(a[i], bf[j], acc[i][j]);
    }
    __syncthreads();
  }

#pragma unroll
  for (int i = 0; i < 8; ++i) {
    const int q = q0 + ((i < 4) ? (ty * 4 + i) : (64 + ty * 4 + (i - 4)));
#pragma unroll
    for (int jh = 0; jh < 2; ++jh) {
      const int mbase = m0 + jh * 64 + tx * 4;
      const int bp = mbase >> 4;
      const int e0 = mbase & 15;
      const size_t o = (size_t)bp * (NN2 * EE) + (size_t)q * EE + e0;
      float4 r4 = *reinterpret_cast<const float4*>(&out[o]);
      float4 w;
      w.x = fmaxf(r4.x + acc[i][jh * 4 + 0], 0.f);
      w.y = fmaxf(r4.y + acc[i][jh * 4 + 1], 0.f);
      w.z = fmaxf(r4.z + acc[i][jh * 4 + 2], 0.f);
      w.w = fmaxf(r4.w + acc[i][jh * 4 + 3], 0.f);
      *reinterpret_cast<float4*>(&out[o]) = w;
    }
  }
}

// ---------------------------------------------------------------------------
extern "C" void kernel_launch(void* const* d_in, const int* in_sizes, int n_in,
                              void* d_out, int out_size, void* d_ws, size_t ws_size,
                              hipStream_t stream) {
  const float* x    = (const float*)d_in[0];
  const float* adj0 = (const float*)d_in[1];
  const float* adj1 = (const float*)d_in[2];
  const float* W    = (const float*)d_in[3];
  const float* bW   = (const float*)d_in[4];
  const float* Ws0  = (const float*)d_in[5];
  const float* bs0  = (const float*)d_in[6];
  const float* Ws1  = (const float*)d_in[7];
  const float* bs1  = (const float*)d_in[8];
  const float* Ws01 = (const float*)d_in[9];
  const float* bs01 = (const float*)d_in[10];
  float* out = (float*)d_out;

  const size_t SLICE = (size_t)NN1 * NCOL;              // per-batch elements
  const size_t AT_BYTES = (size_t)1024 * 1024 * 2;      // adj0^T bf16
  const size_t XT_B     = (size_t)NCOL * 1024 * 2;      // per-batch Xt bf16
  const size_t Y0_B     = SLICE * 4;                    // per-batch y0 fp32
  const size_t PER_B    = XT_B + Y0_B;

  int nb_max = (int)((ws_size > AT_BYTES ? ws_size - AT_BYTES : 0) / PER_B);
  if (nb_max > BB) nb_max = BB;
  if (nb_max < 1)  nb_max = 1;

  ushort* At = (ushort*)d_ws;
  ushort* Xt = (ushort*)((char*)d_ws + AT_BYTES);
  float*  y0 = (float*)((char*)d_ws + AT_BYTES + (size_t)nb_max * XT_B);

  // adj0^T -> bf16 (once)
  k_prep<<<dim3(16, 16, 1), 256, 0, stream>>>(adj0, At, 1024, 0, 0);

  for (int c0 = 0; c0 < BB; c0 += nb_max) {
    const int nb = (BB - c0 < nb_max) ? (BB - c0) : nb_max;
    const float* xc = x   + (size_t)c0 * SLICE;
    float*       oc = out + (size_t)c0 * SLICE;

    // X^T -> bf16 per batch
    k_prep<<<dim3(NCOL / 64, 16, nb), 256, 0, stream>>>(
        xc, Xt, NCOL, SLICE, (size_t)NCOL * 1024);

    dim3 g1(nb * 32, 8);
    k_mode0_mfma<<<g1, 256, 0, stream>>>(At, Xt, y0);

    k_proj<<<dim3(nb * NN1), 256, 0, stream>>>(xc, y0, W, bW, Ws0, bs0,
                                               Ws1, bs1, Ws01, bs01, oc);

    dim3 g3(NN2 / 128, nb * NN1 * EE / 128);
    k_mode1<<<g3, 256, 0, stream>>>(y0, adj1, oc);
  }
}

// Round 4
// 407.420 us; speedup vs baseline: 8.4647x; 1.1949x over previous
//
#include <hip/hip_runtime.h>

#define BB  8
#define NN1 1024
#define NN2 256
#define DD  16
#define EE  16
#define NCOL (NN2 * DD)   // 4096

using bf16x8 = __attribute__((ext_vector_type(8))) short;
using f32x4  = __attribute__((ext_vector_type(4))) float;

__device__ __forceinline__ ushort f2bf(float x) {
  unsigned u = __float_as_uint(x);
  unsigned r = (u + 0x7FFFu + ((u >> 16) & 1u)) >> 16;
  return (ushort)r;
}

#define GLDS16(g, l)                                                       \
  __builtin_amdgcn_global_load_lds(                                        \
      (const __attribute__((address_space(1))) void*)(g),                  \
      (__attribute__((address_space(3))) void*)(l), 16, 0, 0)

// ---------------------------------------------------------------------------
// k_prep: transpose + fp32->bf16 + 16B-chunk swizzle (chunk g <- g ^ ((row>>1)&3)
// within each 64B block). src fp32 [kd(k)][nr], dst bf16 [nr][kd].
// ---------------------------------------------------------------------------
__global__ __launch_bounds__(256)
void k_prep(const float* __restrict__ src, ushort* __restrict__ dst,
            int nr, int kd, size_t srcBatch, size_t dstBatch) {
  __shared__ float tile[64][65];
  const int t = threadIdx.x;
  const int r0 = blockIdx.x * 64;
  const int k0 = blockIdx.y * 64;
  const float* s = src + (size_t)blockIdx.z * srcBatch;
  ushort* d = dst + (size_t)blockIdx.z * dstBatch;

#pragma unroll
  for (int it = 0; it < 4; ++it) {
    const int kr = it * 16 + (t >> 4);
    const int rc = (t & 15) * 4;
    float4 v = *reinterpret_cast<const float4*>(&s[(size_t)(k0 + kr) * nr + r0 + rc]);
    tile[kr][rc] = v.x; tile[kr][rc + 1] = v.y;
    tile[kr][rc + 2] = v.z; tile[kr][rc + 3] = v.w;
  }
  __syncthreads();

#pragma unroll
  for (int pass = 0; pass < 2; ++pass) {
    const int task = t + pass * 256;
    const int pr = task >> 3;   // local row 0..63
    const int gl = task & 7;    // 16B chunk within 64-k span
    const int r = r0 + pr;
    const int f = (r >> 1) & 3;
    const int klb = (gl >> 2) * 32 + ((gl & 3) ^ f) * 8;
    unsigned w[4];
#pragma unroll
    for (int e2 = 0; e2 < 4; ++e2) {
      const ushort lo = f2bf(tile[klb + e2 * 2][pr]);
      const ushort hi = f2bf(tile[klb + e2 * 2 + 1][pr]);
      w[e2] = (unsigned)lo | ((unsigned)hi << 16);
    }
    *reinterpret_cast<uint4*>(&d[(size_t)r * kd + k0 + gl * 8]) =
        *reinterpret_cast<const uint4*>(w);
  }
}

// ---------------------------------------------------------------------------
// k_mode0_mfma: Y[b][p][c] = sum_k adj0[k][p] * X[b][k][c]  (fp32 out)
// 128x128 tile, BK=32, 4 waves (2x2), each wave 4x4 of 16x16x32 MFMA.
// ---------------------------------------------------------------------------
__global__ __launch_bounds__(256)
void k_mode0_mfma(const ushort* __restrict__ At, const ushort* __restrict__ Xt,
                  float* __restrict__ Y) {
  __shared__ ushort As[128 * 32];
  __shared__ ushort Bs[128 * 32];

  const int t = threadIdx.x;
  const int lane = t & 63;
  const int wid = t >> 6;
  const int wm = wid >> 1, wn = wid & 1;
  const int b  = blockIdx.x >> 5;
  const int c0 = (blockIdx.x & 31) << 7;
  const int p0 = blockIdx.y << 7;

  const ushort* Bb = Xt + (size_t)b * (NCOL * 1024);

  f32x4 acc[4][4];
#pragma unroll
  for (int i = 0; i < 4; ++i)
#pragma unroll
    for (int j = 0; j < 4; ++j) acc[i][j] = (f32x4)0.f;

  const int srow = wid * 32 + (lane >> 2);
  const int schk = (lane & 3) * 8;
  const size_t aoff0 = (size_t)(p0 + srow) * 1024 + schk;
  const size_t boff0 = (size_t)(c0 + srow) * 1024 + schk;
  ushort* lA0 = As + (wid * 32) * 32;
  ushort* lA1 = As + (wid * 32 + 16) * 32;
  ushort* lB0 = Bs + (wid * 32) * 32;
  ushort* lB1 = Bs + (wid * 32 + 16) * 32;

  const int lm = lane & 15, g = lane >> 4;
  int aro[4], bro[4];
#pragma unroll
  for (int f = 0; f < 4; ++f) {
    const int ra = wm * 64 + f * 16 + lm;
    aro[f] = ra * 32 + ((g ^ ((ra >> 1) & 3)) << 3);
    const int rb = wn * 64 + f * 16 + lm;
    bro[f] = rb * 32 + ((g ^ ((rb >> 1) & 3)) << 3);
  }

  for (int k0 = 0; k0 < 1024; k0 += 32) {
    GLDS16(At + aoff0 + k0, lA0);
    GLDS16(At + aoff0 + 16 * 1024 + k0, lA1);
    GLDS16(Bb + boff0 + k0, lB0);
    GLDS16(Bb + boff0 + 16 * 1024 + k0, lB1);
    asm volatile("s_waitcnt vmcnt(0)" ::: "memory");
    __syncthreads();

    bf16x8 af[4], bfr[4];
#pragma unroll
    for (int f = 0; f < 4; ++f) af[f] = *reinterpret_cast<const bf16x8*>(As + aro[f]);
#pragma unroll
    for (int f = 0; f < 4; ++f) bfr[f] = *reinterpret_cast<const bf16x8*>(Bs + bro[f]);

#pragma unroll
    for (int i = 0; i < 4; ++i)
#pragma unroll
      for (int j = 0; j < 4; ++j)
        acc[i][j] = __builtin_amdgcn_mfma_f32_16x16x32_bf16(af[i], bfr[j], acc[i][j], 0, 0, 0);
    __syncthreads();
  }

  float* Yb = Y + (size_t)b * (NN1 * NCOL);
  const int orow = (lane >> 4) * 4;
  const int ocol = lane & 15;
#pragma unroll
  for (int i = 0; i < 4; ++i)
#pragma unroll
    for (int j = 0; j < 4; ++j) {
      const int p = p0 + wm * 64 + i * 16 + orow;
      const int c = c0 + wn * 64 + j * 16 + ocol;
      float* dst = Yb + (size_t)p * NCOL + c;
#pragma unroll
      for (int e = 0; e < 4; ++e) dst[(size_t)e * NCOL] = acc[i][j][e];
    }
}

// ---------------------------------------------------------------------------
// k_proj: per (b,p) slice, thread j:
//   r[j,e] = x@W + y0@W_s0 + sum(bias)  -> out (fp32)
//   s[j,e] = x@W_s1 + y0@W_s01          -> st  (bf16, swizzled, [bp][e][j])
// ---------------------------------------------------------------------------
__global__ __launch_bounds__(256)
void k_proj(const float* __restrict__ x, const float* __restrict__ y0,
            ushort* __restrict__ st,
            const float* __restrict__ W,   const float* __restrict__ bW,
            const float* __restrict__ W0,  const float* __restrict__ b0,
            const float* __restrict__ W1,  const float* __restrict__ b1,
            const float* __restrict__ W01, const float* __restrict__ b01,
            float* __restrict__ out) {
  __shared__ float sW[4][DD][EE];
  __shared__ float sbias[EE];

  const int t = threadIdx.x;
  {
    const int m = t >> 6;
    const int r = t & 63;
    const float* Wp = (m == 0) ? W : (m == 1) ? W0 : (m == 2) ? W1 : W01;
    reinterpret_cast<float4*>(&sW[m][0][0])[r] =
        reinterpret_cast<const float4*>(Wp)[r];
  }
  if (t < EE) sbias[t] = bW[t] + b0[t] + b1[t] + b01[t];
  __syncthreads();

  const size_t base = (size_t)blockIdx.x * NCOL + (size_t)t * DD;

  float xr[DD], yr[DD];
#pragma unroll
  for (int v = 0; v < 4; ++v) {
    *reinterpret_cast<float4*>(&xr[v * 4]) =
        *reinterpret_cast<const float4*>(&x[base + v * 4]);
    *reinterpret_cast<float4*>(&yr[v * 4]) =
        *reinterpret_cast<const float4*>(&y0[base + v * 4]);
  }

  float r[EE], s[EE];
#pragma unroll
  for (int e = 0; e < EE; ++e) { r[e] = sbias[e]; s[e] = 0.f; }

#pragma unroll
  for (int d = 0; d < DD; ++d) {
    const float xd = xr[d], yd = yr[d];
#pragma unroll
    for (int e = 0; e < EE; ++e) {
      r[e] = fmaf(xd, sW[0][d][e], r[e]);
      r[e] = fmaf(yd, sW[1][d][e], r[e]);
      s[e] = fmaf(xd, sW[2][d][e], s[e]);
      s[e] = fmaf(yd, sW[3][d][e], s[e]);
    }
  }

#pragma unroll
  for (int v = 0; v < 4; ++v)
    *reinterpret_cast<float4*>(&out[base + v * 4]) =
        *reinterpret_cast<const float4*>(&r[v * 4]);

  // st row = bp*16+e (bp = blockIdx.x), 256 bf16 per row, chunk-swizzled:
  // within each 64B block, phys chunk = ((j>>3)&3) ^ ((row>>1)&3)
  const size_t stbase = (size_t)blockIdx.x * (EE * NN2);
#pragma unroll
  for (int e = 0; e < EE; ++e) {
    const int f = (e >> 1) & 3;
    const int off = (t >> 5) * 32 + ((((t >> 3) & 3) ^ f) << 3) + (t & 7);
    st[stbase + (size_t)e * NN2 + off] = f2bf(s[e]);
  }
}

// ---------------------------------------------------------------------------
// k_mode1_mfma: C[q][m] = sum_j adj1t[q][j] * st[m][j]   (m = bp*16+e)
// then out[bp][q][e] = relu(out + C).  128q x 128m tile, K=256, BK=32.
// ---------------------------------------------------------------------------
__global__ __launch_bounds__(256)
void k_mode1_mfma(const ushort* __restrict__ A1t, const ushort* __restrict__ st,
                  float* __restrict__ out) {
  __shared__ ushort As[128 * 32];
  __shared__ ushort Bs[128 * 32];

  const int t = threadIdx.x;
  const int lane = t & 63;
  const int wid = t >> 6;
  const int wm = wid >> 1, wn = wid & 1;
  const int m0 = blockIdx.x << 7;
  const int q0 = blockIdx.y << 7;

  f32x4 acc[4][4];
#pragma unroll
  for (int i = 0; i < 4; ++i)
#pragma unroll
    for (int j = 0; j < 4; ++j) acc[i][j] = (f32x4)0.f;

  const int srow = wid * 32 + (lane >> 2);
  const int schk = (lane & 3) * 8;
  const size_t aoff0 = (size_t)(q0 + srow) * 256 + schk;
  const size_t boff0 = (size_t)(m0 + srow) * 256 + schk;
  ushort* lA0 = As + (wid * 32) * 32;
  ushort* lA1 = As + (wid * 32 + 16) * 32;
  ushort* lB0 = Bs + (wid * 32) * 32;
  ushort* lB1 = Bs + (wid * 32 + 16) * 32;

  const int lm = lane & 15, g = lane >> 4;
  int aro[4], bro[4];
#pragma unroll
  for (int f = 0; f < 4; ++f) {
    const int ra = wm * 64 + f * 16 + lm;
    aro[f] = ra * 32 + ((g ^ ((ra >> 1) & 3)) << 3);
    const int rb = wn * 64 + f * 16 + lm;
    bro[f] = rb * 32 + ((g ^ ((rb >> 1) & 3)) << 3);
  }

  for (int k0 = 0; k0 < 256; k0 += 32) {
    GLDS16(A1t + aoff0 + k0, lA0);
    GLDS16(A1t + aoff0 + 16 * 256 + k0, lA1);
    GLDS16(st + boff0 + k0, lB0);
    GLDS16(st + boff0 + 16 * 256 + k0, lB1);
    asm volatile("s_waitcnt vmcnt(0)" ::: "memory");
    __syncthreads();

    bf16x8 af[4], bfr[4];
#pragma unroll
    for (int f = 0; f < 4; ++f) af[f] = *reinterpret_cast<const bf16x8*>(As + aro[f]);
#pragma unroll
    for (int f = 0; f < 4; ++f) bfr[f] = *reinterpret_cast<const bf16x8*>(Bs + bro[f]);

#pragma unroll
    for (int i = 0; i < 4; ++i)
#pragma unroll
      for (int j = 0; j < 4; ++j)
        acc[i][j] = __builtin_amdgcn_mfma_f32_16x16x32_bf16(af[i], bfr[j], acc[i][j], 0, 0, 0);
    __syncthreads();
  }

  const int orow = (lane >> 4) * 4;   // -> q offset (row)
  const int ocol = lane & 15;         // -> m offset (col)
#pragma unroll
  for (int i = 0; i < 4; ++i)
#pragma unroll
    for (int j = 0; j < 4; ++j) {
      const int q = q0 + wm * 64 + i * 16 + orow;
      const int m = m0 + wn * 64 + j * 16 + ocol;
      const int bp = m >> 4, e = m & 15;
      float* dst = out + (size_t)bp * (NN2 * EE) + (size_t)q * EE + e;
#pragma unroll
      for (int r = 0; r < 4; ++r)
        dst[r * EE] = fmaxf(dst[r * EE] + acc[i][j][r], 0.f);
    }
}

// ---------------------------------------------------------------------------
extern "C" void kernel_launch(void* const* d_in, const int* in_sizes, int n_in,
                              void* d_out, int out_size, void* d_ws, size_t ws_size,
                              hipStream_t stream) {
  const float* x    = (const float*)d_in[0];
  const float* adj0 = (const float*)d_in[1];
  const float* adj1 = (const float*)d_in[2];
  const float* W    = (const float*)d_in[3];
  const float* bW   = (const float*)d_in[4];
  const float* Ws0  = (const float*)d_in[5];
  const float* bs0  = (const float*)d_in[6];
  const float* Ws1  = (const float*)d_in[7];
  const float* bs1  = (const float*)d_in[8];
  const float* Ws01 = (const float*)d_in[9];
  const float* bs01 = (const float*)d_in[10];
  float* out = (float*)d_out;

  const size_t SLICE = (size_t)NN1 * NCOL;
  const size_t AT_B  = (size_t)1024 * 1024 * 2;       // adj0^T bf16
  const size_t A1T_B = (size_t)256 * 256 * 2;         // adj1^T bf16
  const size_t XT_B  = (size_t)NCOL * 1024 * 2;       // per-batch, 8.4 MB
  const size_t Y0_B  = SLICE * 4;                     // per-batch, 16.8 MB
  const size_t ST_B  = (size_t)NN1 * EE * NN2 * 2;    // per-batch, 8.4 MB
  const size_t HEAD  = AT_B + A1T_B;
  const size_t PER_B = XT_B + Y0_B + ST_B;

  int nb_max = (int)((ws_size > HEAD ? ws_size - HEAD : 0) / PER_B);
  if (nb_max > BB) nb_max = BB;
  if (nb_max < 1)  nb_max = 1;

  ushort* At  = (ushort*)d_ws;
  ushort* A1t = (ushort*)((char*)d_ws + AT_B);
  ushort* Xt  = (ushort*)((char*)d_ws + HEAD);
  float*  y0  = (float*)((char*)d_ws + HEAD + (size_t)nb_max * XT_B);
  ushort* st  = (ushort*)((char*)d_ws + HEAD + (size_t)nb_max * (XT_B + Y0_B));

  k_prep<<<dim3(16, 16, 1), 256, 0, stream>>>(adj0, At, 1024, 1024, 0, 0);
  k_prep<<<dim3(4, 4, 1), 256, 0, stream>>>(adj1, A1t, 256, 256, 0, 0);

  for (int c0 = 0; c0 < BB; c0 += nb_max) {
    const int nb = (BB - c0 < nb_max) ? (BB - c0) : nb_max;
    const float* xc = x   + (size_t)c0 * SLICE;
    float*       oc = out + (size_t)c0 * SLICE;

    k_prep<<<dim3(NCOL / 64, 16, nb), 256, 0, stream>>>(
        xc, Xt, NCOL, 1024, SLICE, (size_t)NCOL * 1024);

    dim3 g1(nb * 32, 8);
    k_mode0_mfma<<<g1, 256, 0, stream>>>(At, Xt, y0);

    k_proj<<<dim3(nb * NN1), 256, 0, stream>>>(xc, y0, st, W, bW, Ws0, bs0,
                                               Ws1, bs1, Ws01, bs01, oc);

    dim3 g3(nb * 128, 2);
    k_mode1_mfma<<<g3, 256, 0, stream>>>(A1t, st, oc);
  }
}

// Round 5
// 275.913 us; speedup vs baseline: 12.4991x; 1.4766x over previous
//
#include <hip/hip_runtime.h>

#define BB  8
#define NN1 1024
#define NN2 256
#define DD  16
#define EE  16
#define NCOL (NN2 * DD)   // 4096

using bf16x8  = __attribute__((ext_vector_type(8))) short;
using f32x4   = __attribute__((ext_vector_type(4))) float;
using ushort8 = __attribute__((ext_vector_type(8))) unsigned short;

__device__ __forceinline__ ushort f2bf(float x) {
  unsigned u = __float_as_uint(x);
  unsigned r = (u + 0x7FFFu + ((u >> 16) & 1u)) >> 16;
  return (ushort)r;
}
__device__ __forceinline__ float bf2f(ushort u) {
  return __uint_as_float((unsigned)u << 16);
}

#define GLDS16(g, l)                                                       \
  __builtin_amdgcn_global_load_lds(                                        \
      (const __attribute__((address_space(1))) void*)(g),                  \
      (__attribute__((address_space(3))) void*)(l), 16, 0, 0)

// ---------------------------------------------------------------------------
// k_prep: transpose + fp32->bf16 + 16B-chunk swizzle (chunk g <- g ^ ((row>>1)&3)
// within each 64B block). src fp32 [kd(k)][nr], dst bf16 [nr][kd].
// ---------------------------------------------------------------------------
__global__ __launch_bounds__(256)
void k_prep(const float* __restrict__ src, ushort* __restrict__ dst,
            int nr, int kd, size_t srcBatch, size_t dstBatch) {
  __shared__ float tile[64][65];
  const int t = threadIdx.x;
  const int r0 = blockIdx.x * 64;
  const int k0 = blockIdx.y * 64;
  const float* s = src + (size_t)blockIdx.z * srcBatch;
  ushort* d = dst + (size_t)blockIdx.z * dstBatch;

#pragma unroll
  for (int it = 0; it < 4; ++it) {
    const int kr = it * 16 + (t >> 4);
    const int rc = (t & 15) * 4;
    float4 v = *reinterpret_cast<const float4*>(&s[(size_t)(k0 + kr) * nr + r0 + rc]);
    tile[kr][rc] = v.x; tile[kr][rc + 1] = v.y;
    tile[kr][rc + 2] = v.z; tile[kr][rc + 3] = v.w;
  }
  __syncthreads();

#pragma unroll
  for (int pass = 0; pass < 2; ++pass) {
    const int task = t + pass * 256;
    const int pr = task >> 3;
    const int gl = task & 7;
    const int r = r0 + pr;
    const int f = (r >> 1) & 3;
    const int klb = (gl >> 2) * 32 + ((gl & 3) ^ f) * 8;
    unsigned w[4];
#pragma unroll
    for (int e2 = 0; e2 < 4; ++e2) {
      const ushort lo = f2bf(tile[klb + e2 * 2][pr]);
      const ushort hi = f2bf(tile[klb + e2 * 2 + 1][pr]);
      w[e2] = (unsigned)lo | ((unsigned)hi << 16);
    }
    *reinterpret_cast<uint4*>(&d[(size_t)r * kd + k0 + gl * 8]) =
        *reinterpret_cast<const uint4*>(w);
  }
}

// ---------------------------------------------------------------------------
// k_mode0_mfma: Y[b][p][c] = sum_k adj0[k][p] * X[b][k][c]  -> bf16 out now
// 128x128 tile, BK=32, 4 waves (2x2), each wave 4x4 of 16x16x32 MFMA.
// ---------------------------------------------------------------------------
__global__ __launch_bounds__(256)
void k_mode0_mfma(const ushort* __restrict__ At, const ushort* __restrict__ Xt,
                  ushort* __restrict__ Y) {
  __shared__ ushort As[128 * 32];
  __shared__ ushort Bs[128 * 32];

  const int t = threadIdx.x;
  const int lane = t & 63;
  const int wid = t >> 6;
  const int wm = wid >> 1, wn = wid & 1;
  const int b  = blockIdx.x >> 5;
  const int c0 = (blockIdx.x & 31) << 7;
  const int p0 = blockIdx.y << 7;

  const ushort* Bb = Xt + (size_t)b * (NCOL * 1024);

  f32x4 acc[4][4];
#pragma unroll
  for (int i = 0; i < 4; ++i)
#pragma unroll
    for (int j = 0; j < 4; ++j) acc[i][j] = (f32x4)0.f;

  const int srow = wid * 32 + (lane >> 2);
  const int schk = (lane & 3) * 8;
  const size_t aoff0 = (size_t)(p0 + srow) * 1024 + schk;
  const size_t boff0 = (size_t)(c0 + srow) * 1024 + schk;
  ushort* lA0 = As + (wid * 32) * 32;
  ushort* lA1 = As + (wid * 32 + 16) * 32;
  ushort* lB0 = Bs + (wid * 32) * 32;
  ushort* lB1 = Bs + (wid * 32 + 16) * 32;

  const int lm = lane & 15, g = lane >> 4;
  int aro[4], bro[4];
#pragma unroll
  for (int f = 0; f < 4; ++f) {
    const int ra = wm * 64 + f * 16 + lm;
    aro[f] = ra * 32 + ((g ^ ((ra >> 1) & 3)) << 3);
    const int rb = wn * 64 + f * 16 + lm;
    bro[f] = rb * 32 + ((g ^ ((rb >> 1) & 3)) << 3);
  }

  for (int k0 = 0; k0 < 1024; k0 += 32) {
    GLDS16(At + aoff0 + k0, lA0);
    GLDS16(At + aoff0 + 16 * 1024 + k0, lA1);
    GLDS16(Bb + boff0 + k0, lB0);
    GLDS16(Bb + boff0 + 16 * 1024 + k0, lB1);
    asm volatile("s_waitcnt vmcnt(0)" ::: "memory");
    __syncthreads();

    bf16x8 af[4], bfr[4];
#pragma unroll
    for (int f = 0; f < 4; ++f) af[f] = *reinterpret_cast<const bf16x8*>(As + aro[f]);
#pragma unroll
    for (int f = 0; f < 4; ++f) bfr[f] = *reinterpret_cast<const bf16x8*>(Bs + bro[f]);

#pragma unroll
    for (int i = 0; i < 4; ++i)
#pragma unroll
      for (int j = 0; j < 4; ++j)
        acc[i][j] = __builtin_amdgcn_mfma_f32_16x16x32_bf16(af[i], bfr[j], acc[i][j], 0, 0, 0);
    __syncthreads();
  }

  ushort* Yb = Y + (size_t)b * (NN1 * NCOL);
  const int orow = (lane >> 4) * 4;
  const int ocol = lane & 15;
#pragma unroll
  for (int i = 0; i < 4; ++i)
#pragma unroll
    for (int j = 0; j < 4; ++j) {
      const int p = p0 + wm * 64 + i * 16 + orow;
      const int c = c0 + wn * 64 + j * 16 + ocol;
      ushort* dst = Yb + (size_t)p * NCOL + c;
#pragma unroll
      for (int e = 0; e < 4; ++e) dst[(size_t)e * NCOL] = f2bf(acc[i][j][e]);
    }
}

// ---------------------------------------------------------------------------
// k_proj: per (b,p) slice, thread j:
//   r[j,e] = x@W + y0@W_s0 + sum(bias)  -> rb (bf16, [bp][j][e])
//   s[j,e] = x@W_s1 + y0@W_s01          -> st (bf16, swizzled, [bp*16+e][j])
// ---------------------------------------------------------------------------
__global__ __launch_bounds__(256)
void k_proj(const float* __restrict__ x, const ushort* __restrict__ y0,
            ushort* __restrict__ st, ushort* __restrict__ rb,
            const float* __restrict__ W,   const float* __restrict__ bW,
            const float* __restrict__ W0,  const float* __restrict__ b0,
            const float* __restrict__ W1,  const float* __restrict__ b1,
            const float* __restrict__ W01, const float* __restrict__ b01) {
  __shared__ float sW[4][DD][EE];
  __shared__ float sbias[EE];

  const int t = threadIdx.x;
  {
    const int m = t >> 6;
    const int r = t & 63;
    const float* Wp = (m == 0) ? W : (m == 1) ? W0 : (m == 2) ? W1 : W01;
    reinterpret_cast<float4*>(&sW[m][0][0])[r] =
        reinterpret_cast<const float4*>(Wp)[r];
  }
  if (t < EE) sbias[t] = bW[t] + b0[t] + b1[t] + b01[t];
  __syncthreads();

  const size_t base = (size_t)blockIdx.x * NCOL + (size_t)t * DD;

  float xr[DD], yr[DD];
#pragma unroll
  for (int v = 0; v < 4; ++v)
    *reinterpret_cast<float4*>(&xr[v * 4]) =
        *reinterpret_cast<const float4*>(&x[base + v * 4]);
  {
    ushort8 ya = *reinterpret_cast<const ushort8*>(&y0[base]);
    ushort8 yb = *reinterpret_cast<const ushort8*>(&y0[base + 8]);
#pragma unroll
    for (int k = 0; k < 8; ++k) { yr[k] = bf2f(ya[k]); yr[8 + k] = bf2f(yb[k]); }
  }

  float r[EE], s[EE];
#pragma unroll
  for (int e = 0; e < EE; ++e) { r[e] = sbias[e]; s[e] = 0.f; }

#pragma unroll
  for (int d = 0; d < DD; ++d) {
    const float xd = xr[d], yd = yr[d];
#pragma unroll
    for (int e = 0; e < EE; ++e) {
      r[e] = fmaf(xd, sW[0][d][e], r[e]);
      r[e] = fmaf(yd, sW[1][d][e], r[e]);
      s[e] = fmaf(xd, sW[2][d][e], s[e]);
      s[e] = fmaf(yd, sW[3][d][e], s[e]);
    }
  }

  // r -> bf16, same layout as out: [bp][j][e]
  {
    ushort rw[16];
#pragma unroll
    for (int e = 0; e < EE; ++e) rw[e] = f2bf(r[e]);
    *reinterpret_cast<uint4*>(&rb[base])     = *reinterpret_cast<const uint4*>(&rw[0]);
    *reinterpret_cast<uint4*>(&rb[base + 8]) = *reinterpret_cast<const uint4*>(&rw[8]);
  }

  // st row = bp*16+e, chunk-swizzled within 64B blocks
  const size_t stbase = (size_t)blockIdx.x * (EE * NN2);
#pragma unroll
  for (int e = 0; e < EE; ++e) {
    const int f = (e >> 1) & 3;
    const int off = (t >> 5) * 32 + ((((t >> 3) & 3) ^ f) << 3) + (t & 7);
    st[stbase + (size_t)e * NN2 + off] = f2bf(s[e]);
  }
}

// ---------------------------------------------------------------------------
// k_mode1_mfma: C[q][m] = sum_j adj1t[q][j] * st[m][j]   (m = bp*16+e)
// out[bp][q][e] = relu(rb + C)  -- single write, rb pre-staged to LDS (T14)
// ---------------------------------------------------------------------------
__global__ __launch_bounds__(256)
void k_mode1_mfma(const ushort* __restrict__ A1t, const ushort* __restrict__ st,
                  const ushort* __restrict__ rb, float* __restrict__ out) {
  __shared__ ushort As[128 * 32];
  __shared__ ushort Bs[128 * 32];
  __shared__ ushort Rs[8 * 128 * 16];   // 32 KB: [bp_local][q_local][e]

  const int t = threadIdx.x;
  const int lane = t & 63;
  const int wid = t >> 6;
  const int wm = wid >> 1, wn = wid & 1;
  const int m0 = blockIdx.x << 7;
  const int q0 = blockIdx.y << 7;
  const int bp0 = m0 >> 4;

  // T14: issue the whole 32 KB r-tile stage before the K-loop; the K-loop's
  // first vmcnt(0) drains it, the final barrier orders it before epilogue.
  {
#pragma unroll
    for (int k = 0; k < 8; ++k) {
      const int unit = k * 256 + wid * 64 + lane;     // 16B units, 0..2047
      const int bpl = unit >> 8;                      // 256 units per bp chunk
      const ushort* gsrc = rb + (size_t)(bp0 + bpl) * (NN2 * EE)
                              + (size_t)q0 * EE + (unit & 255) * 8;
      GLDS16(gsrc, Rs + (size_t)(k * 256 + wid * 64) * 8);
    }
  }

  f32x4 acc[4][4];
#pragma unroll
  for (int i = 0; i < 4; ++i)
#pragma unroll
    for (int j = 0; j < 4; ++j) acc[i][j] = (f32x4)0.f;

  const int srow = wid * 32 + (lane >> 2);
  const int schk = (lane & 3) * 8;
  const size_t aoff0 = (size_t)(q0 + srow) * 256 + schk;
  const size_t boff0 = (size_t)(m0 + srow) * 256 + schk;
  ushort* lA0 = As + (wid * 32) * 32;
  ushort* lA1 = As + (wid * 32 + 16) * 32;
  ushort* lB0 = Bs + (wid * 32) * 32;
  ushort* lB1 = Bs + (wid * 32 + 16) * 32;

  const int lm = lane & 15, g = lane >> 4;
  int aro[4], bro[4];
#pragma unroll
  for (int f = 0; f < 4; ++f) {
    const int ra = wm * 64 + f * 16 + lm;
    aro[f] = ra * 32 + ((g ^ ((ra >> 1) & 3)) << 3);
    const int rbw = wn * 64 + f * 16 + lm;
    bro[f] = rbw * 32 + ((g ^ ((rbw >> 1) & 3)) << 3);
  }

  for (int k0 = 0; k0 < 256; k0 += 32) {
    GLDS16(A1t + aoff0 + k0, lA0);
    GLDS16(A1t + aoff0 + 16 * 256 + k0, lA1);
    GLDS16(st + boff0 + k0, lB0);
    GLDS16(st + boff0 + 16 * 256 + k0, lB1);
    asm volatile("s_waitcnt vmcnt(0)" ::: "memory");
    __syncthreads();

    bf16x8 af[4], bfr[4];
#pragma unroll
    for (int f = 0; f < 4; ++f) af[f] = *reinterpret_cast<const bf16x8*>(As + aro[f]);
#pragma unroll
    for (int f = 0; f < 4; ++f) bfr[f] = *reinterpret_cast<const bf16x8*>(Bs + bro[f]);

#pragma unroll
    for (int i = 0; i < 4; ++i)
#pragma unroll
      for (int j = 0; j < 4; ++j)
        acc[i][j] = __builtin_amdgcn_mfma_f32_16x16x32_bf16(af[i], bfr[j], acc[i][j], 0, 0, 0);
    __syncthreads();
  }

  const int orow = (lane >> 4) * 4;   // q offset
  const int ocol = lane & 15;         // m offset
#pragma unroll
  for (int i = 0; i < 4; ++i)
#pragma unroll
    for (int j = 0; j < 4; ++j) {
      const int ml  = wn * 64 + j * 16 + ocol;
      const int bpl = ml >> 4, e = ml & 15;
      const int ql  = wm * 64 + i * 16 + orow;
      const ushort* rsl = Rs + bpl * 2048 + ql * 16 + e;
      float* dst = out + (size_t)(bp0 + bpl) * (NN2 * EE)
                       + (size_t)(q0 + ql) * EE + e;
#pragma unroll
      for (int r = 0; r < 4; ++r)
        dst[r * EE] = fmaxf(bf2f(rsl[r * 16]) + acc[i][j][r], 0.f);
    }
}

// ---------------------------------------------------------------------------
extern "C" void kernel_launch(void* const* d_in, const int* in_sizes, int n_in,
                              void* d_out, int out_size, void* d_ws, size_t ws_size,
                              hipStream_t stream) {
  const float* x    = (const float*)d_in[0];
  const float* adj0 = (const float*)d_in[1];
  const float* adj1 = (const float*)d_in[2];
  const float* W    = (const float*)d_in[3];
  const float* bW   = (const float*)d_in[4];
  const float* Ws0  = (const float*)d_in[5];
  const float* bs0  = (const float*)d_in[6];
  const float* Ws1  = (const float*)d_in[7];
  const float* bs1  = (const float*)d_in[8];
  const float* Ws01 = (const float*)d_in[9];
  const float* bs01 = (const float*)d_in[10];
  float* out = (float*)d_out;

  const size_t SLICE = (size_t)NN1 * NCOL;
  const size_t AT_B  = (size_t)1024 * 1024 * 2;       // adj0^T bf16
  const size_t A1T_B = (size_t)256 * 256 * 2;         // adj1^T bf16
  const size_t XT_B  = (size_t)NCOL * 1024 * 2;       // per-batch, 8.4 MB
  const size_t Y0_B  = SLICE * 2;                     // per-batch, bf16, 8.4 MB
  const size_t ST_B  = SLICE * 2;                     // per-batch, 8.4 MB
  const size_t RB_B  = SLICE * 2;                     // per-batch, 8.4 MB
  const size_t HEAD  = AT_B + A1T_B;
  const size_t PER_B = XT_B + Y0_B + ST_B + RB_B;

  int nb_max = (int)((ws_size > HEAD ? ws_size - HEAD : 0) / PER_B);
  if (nb_max > BB) nb_max = BB;
  if (nb_max < 1)  nb_max = 1;

  ushort* At  = (ushort*)d_ws;
  ushort* A1t = (ushort*)((char*)d_ws + AT_B);
  ushort* Xt  = (ushort*)((char*)d_ws + HEAD);
  ushort* y0  = (ushort*)((char*)d_ws + HEAD + (size_t)nb_max * XT_B);
  ushort* st  = (ushort*)((char*)d_ws + HEAD + (size_t)nb_max * (XT_B + Y0_B));
  ushort* rb  = (ushort*)((char*)d_ws + HEAD + (size_t)nb_max * (XT_B + Y0_B + ST_B));

  k_prep<<<dim3(16, 16, 1), 256, 0, stream>>>(adj0, At, 1024, 1024, 0, 0);
  k_prep<<<dim3(4, 4, 1), 256, 0, stream>>>(adj1, A1t, 256, 256, 0, 0);

  for (int c0 = 0; c0 < BB; c0 += nb_max) {
    const int nb = (BB - c0 < nb_max) ? (BB - c0) : nb_max;
    const float* xc = x   + (size_t)c0 * SLICE;
    float*       oc = out + (size_t)c0 * SLICE;

    k_prep<<<dim3(NCOL / 64, 16, nb), 256, 0, stream>>>(
        xc, Xt, NCOL, 1024, SLICE, (size_t)NCOL * 1024);

    dim3 g1(nb * 32, 8);
    k_mode0_mfma<<<g1, 256, 0, stream>>>(At, Xt, y0);

    k_proj<<<dim3(nb * NN1), 256, 0, stream>>>(xc, y0, st, rb, W, bW, Ws0, bs0,
                                               Ws1, bs1, Ws01, bs01);

    dim3 g3(nb * 128, 2);
    k_mode1_mfma<<<g3, 256, 0, stream>>>(A1t, st, rb, oc);
  }
}